// Round 3
// baseline (549.280 us; speedup 1.0000x reference)
//
#include <hip/hip_runtime.h>
#include <hip/hip_bf16.h>
#include <stdint.h>

// LimitRegressor = relu(x@W1+b1)@W2+b2 followed by a fixed-point iteration
// whose unique fixed point is y*=out (tanh contraction, global early-exit at
// eps=1e-6 fires at k~13 with residual < 3e-7 << the 6.09e-2 threshold).
// So we emit out directly: two bf16 MFMA GEMMs.
//
// GEMM: 256x256 tile, BK=64, 8 waves (2Mx4N), double-buffered 128KiB LDS,
// software-pipelined 8-phase/2-K-tile loop: phase p issues MFMAs on regs
// loaded in phase p-1 while ds_reading phase p+1's frags (LDS || MFMA pipe
// overlap), staging 1 half-tile/phase with uniform counted vmcnt(4) (never 0;
// every stage->read distance = 3 phases; per-wave vmcnt + barrier certifies
// collective visibility). T1 XCD swizzle, T2 LDS XOR swizzle, T5 setprio.

#define DEV __device__ __forceinline__

typedef short bf16x8 __attribute__((ext_vector_type(8)));
typedef float f32x4 __attribute__((ext_vector_type(4)));

typedef __attribute__((address_space(1))) const unsigned char* gptr1_t;
typedef __attribute__((address_space(3))) unsigned char* lptr3_t;

DEV void async_copy16(const void* g, void* l) {
  __builtin_amdgcn_global_load_lds((gptr1_t)g, (lptr3_t)l, 16, 0, 0);
}

DEV unsigned short f2bf(float f) {
  union { float f; unsigned u; } v; v.f = f;
  unsigned u = v.u + 0x7FFFu + ((v.u >> 16) & 1u);  // RNE
  return (unsigned short)(u >> 16);
}

#define BAR()  __builtin_amdgcn_s_barrier()
#define VMW(n) asm volatile("s_waitcnt vmcnt(" #n ")" ::: "memory")

// ---------------- prep kernels ----------------

__global__ void cvt_f32_bf16(const float4* __restrict__ in,
                             ushort4* __restrict__ out, int n4) {
  int i = blockIdx.x * blockDim.x + threadIdx.x;
  if (i >= n4) return;
  float4 v = in[i];
  ushort4 o;
  o.x = f2bf(v.x); o.y = f2bf(v.y); o.z = f2bf(v.z); o.w = f2bf(v.w);
  out[i] = o;
}

// f32 [R][C] row-major  ->  bf16 [C][R] row-major (W -> W^T as bf16)
__global__ void transpose_f32_bf16(const float* __restrict__ in,
                                   unsigned short* __restrict__ out,
                                   int R, int C) {
  __shared__ float tile[32][33];
  int c0 = blockIdx.x * 32, r0 = blockIdx.y * 32;
  int tx = threadIdx.x, ty = threadIdx.y;  // block (32, 8)
#pragma unroll
  for (int i = 0; i < 32; i += 8)
    tile[ty + i][tx] = in[(long)(r0 + ty + i) * C + (c0 + tx)];
  __syncthreads();
#pragma unroll
  for (int i = 0; i < 32; i += 8)
    out[(long)(c0 + ty + i) * R + (r0 + tx)] = f2bf(tile[tx][ty + i]);
}

// ---------------- 256x256 8-wave GEMM, C = A * BT^T + bias ----------------
// LDS per operand per buf: 4 chunks of 8KB; chunk c = rows [c*64,c*64+64) x
// k[0,64) bf16, 16B-chunk XOR swizzle: LDS[row][c16] = global k-chunk
// (c16 ^ (row&7)). Staged with pre-swizzled global source (both-sides rule).

#define LDA(base, m, ks) \
  (*(const bf16x8*)((base) + abase + (m) * 2048 + (c0 ^ ((ks) << 6))))
#define LDB(base, n, ks) \
  (*(const bf16x8*)((base) + bbase + (n) * 2048 + (c0 ^ ((ks) << 6))))

#define RD_A(dst, base, m0_)                                   \
  _Pragma("unroll") for (int m_ = 0; m_ < 4; ++m_) {           \
    dst[m_][0] = LDA(base, (m0_) + m_, 0);                     \
    dst[m_][1] = LDA(base, (m0_) + m_, 1);                     \
  }
#define RD_B(dst, base, n0_)                                   \
  _Pragma("unroll") for (int n_ = 0; n_ < 2; ++n_) {           \
    dst[n_][0] = LDB(base, (n0_) + n_, 0);                     \
    dst[n_][1] = LDB(base, (n0_) + n_, 1);                     \
  }

#define QUAD(MB, NB, AF, BF)                                                \
  do {                                                                      \
    __builtin_amdgcn_s_setprio(1);                                          \
    _Pragma("unroll") for (int m_ = 0; m_ < 4; ++m_)                        \
    _Pragma("unroll") for (int n_ = 0; n_ < 2; ++n_) {                      \
      acc[(MB) + m_][(NB) + n_] = __builtin_amdgcn_mfma_f32_16x16x32_bf16(  \
          AF[m_][0], BF[n_][0], acc[(MB) + m_][(NB) + n_], 0, 0, 0);        \
      acc[(MB) + m_][(NB) + n_] = __builtin_amdgcn_mfma_f32_16x16x32_bf16(  \
          AF[m_][1], BF[n_][1], acc[(MB) + m_][(NB) + n_], 0, 0, 0);        \
    }                                                                       \
    __builtin_amdgcn_s_setprio(0);                                          \
  } while (0)

// stage macros: dstw = per-wave LDS base (buf base + wave*1024), koff = elems
#define ST_A_LO(dstw, koff) { async_copy16(gA[0] + (koff), (dstw));          \
                              async_copy16(gA[2] + (koff), (dstw) + 16384); }
#define ST_A_HI(dstw, koff) { async_copy16(gA[1] + (koff), (dstw) + 8192);   \
                              async_copy16(gA[3] + (koff), (dstw) + 24576); }
#define ST_B_LO(dstw, koff) { async_copy16(gB[0] + (koff), (dstw));          \
                              async_copy16(gB[1] + (koff), (dstw) + 8192); }
#define ST_B_HI(dstw, koff) { async_copy16(gB[2] + (koff), (dstw) + 16384);  \
                              async_copy16(gB[3] + (koff), (dstw) + 24576); }

template <bool RELU_BF16>
__global__ __launch_bounds__(512, 2)
void gemm256(const unsigned short* __restrict__ A,   // bf16 [M][K]
             const unsigned short* __restrict__ BT,  // bf16 [N][K]
             const float* __restrict__ bias,         // [N]
             void* __restrict__ Cout,                // bf16 or f32 [M][N]
             int M, int N, int K, int nbn_shift) {
  extern __shared__ char lds[];
  const char* aE = lds;                 // A buf even tiles
  const char* aO = lds + 32768;         // A buf odd tiles
  const char* bE = lds + 65536;         // B buf even
  const char* bO = lds + 98304;         // B buf odd

  const int tid = threadIdx.x;
  const int wave = tid >> 6, lane = tid & 63;
  const int wr = wave >> 2, wc = wave & 3;  // 2x4 waves, each 128x64 out

  char* aEw = (char*)aE + wave * 1024;
  char* aOw = (char*)aO + wave * 1024;
  char* bEw = (char*)bE + wave * 1024;
  char* bOw = (char*)bO + wave * 1024;

  // T1: XCD-aware block swizzle (grids here are multiples of 8)
  const int nwg = gridDim.x;
  const int wg = blockIdx.x;
  const int swz = (wg & 7) * (nwg >> 3) + (wg >> 3);
  const int bm = swz >> nbn_shift;
  const int bn = swz & ((1 << nbn_shift) - 1);
  const int m0 = bm << 8, n0 = bn << 8;

  // staging addresses (pre-swizzled global source, linear LDS dest)
  const int srow = tid >> 3;
  const int sk = ((tid & 7) ^ (srow & 7)) << 3;
  const unsigned short* gA[4];
  const unsigned short* gB[4];
#pragma unroll
  for (int c = 0; c < 4; ++c) {
    gA[c] = A + (size_t)(m0 + c * 64 + srow) * K + sk;
    gB[c] = BT + (size_t)(n0 + c * 64 + srow) * K + sk;
  }

  // read addresses
  const int lr = lane & 15, lg = lane >> 4;
  const int c0 = ((lg ^ (lr & 7)) << 4);
  const int abase = (wr * 128 + lr) * 128;
  const int bbase = (wc * 64 + lr) * 128;

  f32x4 acc[8][4] = {};
  bf16x8 afl[4][2], afh[4][2], b01E[2][2], b01O[2][2], b23[2][2];

  // ---- prologue: tile0 full (S1..S4) + tile1 A-lo; certify S1..S3 ----
  ST_A_LO(aEw, 0);        // S1^E0
  ST_B_LO(bEw, 0);        // S2^E0
  ST_B_HI(bEw, 0);        // S3^E0
  ST_A_HI(aEw, 0);        // S4^E0
  ST_A_LO(aOw, 64);       // S1^O0
  VMW(4);                 // S1..S3 landed (leaves S4^E0, S1^O0)
  BAR();
  RD_A(afl, aE, 0);       // Q1^E0 operands
  RD_B(b01E, bE, 0);

  const int NT = K >> 6;        // K-tiles (even for both GEMMs)
  const int nIt = NT >> 1;      // 2 tiles per iteration

  for (int it = 0; it < nIt - 1; ++it) {
    const int ko  = (2 * it + 1) << 6;  // tile O   (odd)
    const int ke2 = (2 * it + 2) << 6;  // tile E'  (next even)
    const int ko3 = (2 * it + 3) << 6;  // tile O'  (next odd)
    // P1: MFMA Q1^E; read b23^E; stage S2^O
    ST_B_LO(bOw, ko);  VMW(4);  RD_B(b23, bE, 2);   QUAD(0, 0, afl, b01E);  BAR();
    // P2: Q2^E; read afh^E; stage S3^O
    ST_B_HI(bOw, ko);  VMW(4);  RD_A(afh, aE, 4);   QUAD(0, 2, afl, b23);   BAR();
    // P3: Q3^E; read afl^O; stage S4^O
    ST_A_HI(aOw, ko);  VMW(4);  RD_A(afl, aO, 0);   QUAD(4, 2, afh, b23);   BAR();
    // P4: Q4^E; read b01^O; stage S1^E'
    ST_A_LO(aEw, ke2); VMW(4);  RD_B(b01O, bO, 0);  QUAD(4, 0, afh, b01E);  BAR();
    // P5: Q1^O; read b23^O; stage S2^E'
    ST_B_LO(bEw, ke2); VMW(4);  RD_B(b23, bO, 2);   QUAD(0, 0, afl, b01O);  BAR();
    // P6: Q2^O; read afh^O; stage S3^E'
    ST_B_HI(bEw, ke2); VMW(4);  RD_A(afh, aO, 4);   QUAD(0, 2, afl, b23);   BAR();
    // P7: Q3^O; read afl^E'; stage S4^E'
    ST_A_HI(aEw, ke2); VMW(4);  RD_A(afl, aE, 0);   QUAD(4, 2, afh, b23);   BAR();
    // P8: Q4^O; read b01^E'; stage S1^O'
    ST_A_LO(aOw, ko3); VMW(4);  RD_B(b01E, bE, 0);  QUAD(4, 0, afh, b01O);  BAR();
  }

  // ---- peeled last iteration (tiles NT-2, NT-1): drain 4 -> 2 -> 0 ----
  {
    const int ko = (NT - 1) << 6;
    ST_B_LO(bOw, ko);  VMW(4);  RD_B(b23, bE, 2);   QUAD(0, 0, afl, b01E);  BAR();
    ST_B_HI(bOw, ko);  VMW(4);  RD_A(afh, aE, 4);   QUAD(0, 2, afl, b23);   BAR();
    ST_A_HI(aOw, ko);  VMW(4);  RD_A(afl, aO, 0);   QUAD(4, 2, afh, b23);   BAR();
    VMW(2);            RD_B(b01O, bO, 0);           QUAD(4, 0, afh, b01E);  BAR();
    VMW(0);            RD_B(b23, bO, 2);            QUAD(0, 0, afl, b01O);  BAR();
    RD_A(afh, aO, 4);                               QUAD(0, 2, afl, b23);   BAR();
    QUAD(4, 2, afh, b23);                           BAR();
    QUAD(4, 0, afh, b01O);
  }

  // ---- epilogue. C/D frag: col = lane&15, row = (lane>>4)*4 + j ----
  const int ccol = n0 + wc * 64;
  const int crow = m0 + wr * 128;
  float bv[4];
#pragma unroll
  for (int n = 0; n < 4; ++n) bv[n] = bias[ccol + n * 16 + lr];

  if (RELU_BF16) {
    unsigned short* O = (unsigned short*)Cout;
#pragma unroll
    for (int m = 0; m < 8; ++m)
#pragma unroll
      for (int j = 0; j < 4; ++j) {
        size_t r = (size_t)(crow + m * 16 + lg * 4 + j) * N;
#pragma unroll
        for (int n = 0; n < 4; ++n) {
          float v = acc[m][n][j] + bv[n];
          O[r + ccol + n * 16 + lr] = f2bf(fmaxf(v, 0.0f));
        }
      }
  } else {
    float* O = (float*)Cout;
#pragma unroll
    for (int m = 0; m < 8; ++m)
#pragma unroll
      for (int j = 0; j < 4; ++j) {
        size_t r = (size_t)(crow + m * 16 + lg * 4 + j) * N;
#pragma unroll
        for (int n = 0; n < 4; ++n)
          O[r + ccol + n * 16 + lr] = acc[m][n][j] + bv[n];
      }
  }
}

// ---------------- launch ----------------

extern "C" void kernel_launch(void* const* d_in, const int* in_sizes, int n_in,
                              void* d_out, int out_size, void* d_ws,
                              size_t ws_size, hipStream_t stream) {
  const float* x  = (const float*)d_in[0];   // [16384,1024]
  const float* W1 = (const float*)d_in[1];   // [1024,4096]
  const float* b1 = (const float*)d_in[2];   // [4096]
  const float* W2 = (const float*)d_in[3];   // [4096,1024]
  const float* b2 = (const float*)d_in[4];   // [1024]
  float* out = (float*)d_out;                // [16384,1024] f32

  const int B = 16384, DIN = 1024, DH = 4096, DOUT = 1024;

  size_t need = (size_t)B * DIN * 2 + (size_t)DIN * DH * 2 +
                (size_t)DH * DOUT * 2 + (size_t)B * DH * 2;
  if (ws_size < need) return;

  char* ws = (char*)d_ws;
  unsigned short* xb  = (unsigned short*)ws;  ws += (size_t)B * DIN * 2;
  unsigned short* w1t = (unsigned short*)ws;  ws += (size_t)DIN * DH * 2;  // [DH][DIN]
  unsigned short* w2t = (unsigned short*)ws;  ws += (size_t)DH * DOUT * 2; // [DOUT][DH]
  unsigned short* h   = (unsigned short*)ws;                               // [B][DH]

  hipFuncSetAttribute((const void*)gemm256<true>,
                      hipFuncAttributeMaxDynamicSharedMemorySize, 131072);
  hipFuncSetAttribute((const void*)gemm256<false>,
                      hipFuncAttributeMaxDynamicSharedMemorySize, 131072);

  int n4 = B * DIN / 4;
  cvt_f32_bf16<<<n4 / 256, 256, 0, stream>>>((const float4*)x, (ushort4*)xb, n4);
  transpose_f32_bf16<<<dim3(DH / 32, DIN / 32), dim3(32, 8), 0, stream>>>(W1, w1t, DIN, DH);
  transpose_f32_bf16<<<dim3(DOUT / 32, DH / 32), dim3(32, 8), 0, stream>>>(W2, w2t, DH, DOUT);

  // h = relu(x @ W1 + b1) : M=16384, N=4096, K=1024 (NT=16)
  gemm256<true><<<dim3((B / 256) * (DH / 256)), 512, 131072, stream>>>(
      xb, w1t, b1, h, B, DH, DIN, 4);
  // out = h @ W2 + b2     : M=16384, N=1024, K=4096 (NT=64)
  gemm256<false><<<dim3((B / 256) * (DOUT / 256)), 512, 131072, stream>>>(
      h, w2t, b2, out, B, DOUT, DH, 2);
}

// Round 4
// 280.389 us; speedup vs baseline: 1.9590x; 1.9590x over previous
//
#include <hip/hip_runtime.h>
#include <hip/hip_bf16.h>
#include <stdint.h>

// LimitRegressor = relu(x@W1+b1)@W2+b2 followed by a fixed-point iteration
// whose unique fixed point is y*=out (tanh contraction, global early-exit at
// eps=1e-6 fires at k~13 with residual < 3e-7 << the 6.09e-2 threshold).
// So we emit out directly: two bf16 MFMA GEMMs.
//
// GEMM: 256x256 tile, BK=64, 8 waves (2Mx4N), double-buffered 128KiB LDS,
// m201-style 4-phase/K-tile schedule. Register footprint = round-2 (af/b01/
// b23 reused across quadrants; VGPR~116 + AGPR 128 <= 256 cap, no spill).
// Deep prefetch: A staged 1 tile ahead (P1/P2), B staged 2 tiles ahead
// (P3/P4); waits vmcnt(8) @P2-end, vmcnt(6) @P4-end -> every stage->read
// distance is 3-6 phases (>= L3/HBM latency), never draining to 0 in the
// steady loop. T1 XCD swizzle, T2 LDS XOR swizzle, T5 setprio.

#define DEV __device__ __forceinline__

typedef short bf16x8 __attribute__((ext_vector_type(8)));
typedef float f32x4 __attribute__((ext_vector_type(4)));

typedef __attribute__((address_space(1))) const unsigned char* gptr1_t;
typedef __attribute__((address_space(3))) unsigned char* lptr3_t;

DEV void async_copy16(const void* g, void* l) {
  __builtin_amdgcn_global_load_lds((gptr1_t)g, (lptr3_t)l, 16, 0, 0);
}

DEV unsigned short f2bf(float f) {
  union { float f; unsigned u; } v; v.f = f;
  unsigned u = v.u + 0x7FFFu + ((v.u >> 16) & 1u);  // RNE
  return (unsigned short)(u >> 16);
}

#define BAR()   __builtin_amdgcn_s_barrier()
#define LGKM0() asm volatile("s_waitcnt lgkmcnt(0)" ::: "memory")
#define VMW(n)  asm volatile("s_waitcnt vmcnt(" #n ")" ::: "memory")

// ---------------- prep kernels ----------------

__global__ void cvt_f32_bf16(const float4* __restrict__ in,
                             ushort4* __restrict__ out, int n4) {
  int i = blockIdx.x * blockDim.x + threadIdx.x;
  if (i >= n4) return;
  float4 v = in[i];
  ushort4 o;
  o.x = f2bf(v.x); o.y = f2bf(v.y); o.z = f2bf(v.z); o.w = f2bf(v.w);
  out[i] = o;
}

// f32 [R][C] row-major  ->  bf16 [C][R] row-major (W -> W^T as bf16)
__global__ void transpose_f32_bf16(const float* __restrict__ in,
                                   unsigned short* __restrict__ out,
                                   int R, int C) {
  __shared__ float tile[32][33];
  int c0 = blockIdx.x * 32, r0 = blockIdx.y * 32;
  int tx = threadIdx.x, ty = threadIdx.y;  // block (32, 8)
#pragma unroll
  for (int i = 0; i < 32; i += 8)
    tile[ty + i][tx] = in[(long)(r0 + ty + i) * C + (c0 + tx)];
  __syncthreads();
#pragma unroll
  for (int i = 0; i < 32; i += 8)
    out[(long)(c0 + ty + i) * R + (r0 + tx)] = f2bf(tile[tx][ty + i]);
}

// ---------------- 256x256 8-wave GEMM, C = A * BT^T + bias ----------------
// LDS per operand per buf: 4 chunks of 8KB; chunk c = rows [c*64,c*64+64) x
// k[0,64) bf16, 16B-chunk XOR swizzle: LDS[row][c16] = global k-chunk
// (c16 ^ (row&7)). Staged with pre-swizzled global source (both-sides rule).

#define LDA(base, m, ks) \
  (*(const bf16x8*)((base) + abase + (m) * 2048 + (c0 ^ ((ks) << 6))))
#define LDB(base, n, ks) \
  (*(const bf16x8*)((base) + bbase + (n) * 2048 + (c0 ^ ((ks) << 6))))

#define RD_A(dst, base, m0_)                                   \
  _Pragma("unroll") for (int m_ = 0; m_ < 4; ++m_) {           \
    dst[m_][0] = LDA(base, (m0_) + m_, 0);                     \
    dst[m_][1] = LDA(base, (m0_) + m_, 1);                     \
  }
#define RD_B(dst, base, n0_)                                   \
  _Pragma("unroll") for (int n_ = 0; n_ < 2; ++n_) {           \
    dst[n_][0] = LDB(base, (n0_) + n_, 0);                     \
    dst[n_][1] = LDB(base, (n0_) + n_, 1);                     \
  }

#define QUAD(MB, NB, AF, BF)                                                \
  do {                                                                      \
    __builtin_amdgcn_s_setprio(1);                                          \
    _Pragma("unroll") for (int m_ = 0; m_ < 4; ++m_)                        \
    _Pragma("unroll") for (int n_ = 0; n_ < 2; ++n_) {                      \
      acc[(MB) + m_][(NB) + n_] = __builtin_amdgcn_mfma_f32_16x16x32_bf16(  \
          AF[m_][0], BF[n_][0], acc[(MB) + m_][(NB) + n_], 0, 0, 0);        \
      acc[(MB) + m_][(NB) + n_] = __builtin_amdgcn_mfma_f32_16x16x32_bf16(  \
          AF[m_][1], BF[n_][1], acc[(MB) + m_][(NB) + n_], 0, 0, 0);        \
    }                                                                       \
    __builtin_amdgcn_s_setprio(0);                                          \
  } while (0)

// stage macros: dstw = per-wave LDS base (buf base + wave*1024), koff = elems
#define ST_A_LO(dstw, koff) { async_copy16(gA[0] + (koff), (dstw));          \
                              async_copy16(gA[2] + (koff), (dstw) + 16384); }
#define ST_A_HI(dstw, koff) { async_copy16(gA[1] + (koff), (dstw) + 8192);   \
                              async_copy16(gA[3] + (koff), (dstw) + 24576); }
#define ST_B_LO(dstw, koff) { async_copy16(gB[0] + (koff), (dstw));          \
                              async_copy16(gB[1] + (koff), (dstw) + 8192); }
#define ST_B_HI(dstw, koff) { async_copy16(gB[2] + (koff), (dstw) + 16384);  \
                              async_copy16(gB[3] + (koff), (dstw) + 24576); }

template <bool RELU_BF16>
__global__ __launch_bounds__(512, 2)
void gemm256(const unsigned short* __restrict__ A,   // bf16 [M][K]
             const unsigned short* __restrict__ BT,  // bf16 [N][K]
             const float* __restrict__ bias,         // [N]
             void* __restrict__ Cout,                // bf16 or f32 [M][N]
             int M, int N, int K, int nbn_shift) {
  extern __shared__ char lds[];
  const char* aE = lds;                 // A buf, even tiles
  const char* aO = lds + 32768;         // A buf, odd tiles
  const char* bE = lds + 65536;         // B buf, even
  const char* bO = lds + 98304;         // B buf, odd

  const int tid = threadIdx.x;
  const int wave = tid >> 6, lane = tid & 63;
  const int wr = wave >> 2, wc = wave & 3;  // 2x4 waves, each 128x64 out

  char* aEw = (char*)aE + wave * 1024;
  char* aOw = (char*)aO + wave * 1024;
  char* bEw = (char*)bE + wave * 1024;
  char* bOw = (char*)bO + wave * 1024;

  // T1: XCD-aware block swizzle (grids here are multiples of 8)
  const int nwg = gridDim.x;
  const int wg = blockIdx.x;
  const int swz = (wg & 7) * (nwg >> 3) + (wg >> 3);
  const int bm = swz >> nbn_shift;
  const int bn = swz & ((1 << nbn_shift) - 1);
  const int m0 = bm << 8, n0 = bn << 8;

  // staging addresses (pre-swizzled global source, linear LDS dest)
  const int srow = tid >> 3;
  const int sk = ((tid & 7) ^ (srow & 7)) << 3;
  const unsigned short* gA[4];
  const unsigned short* gB[4];
#pragma unroll
  for (int c = 0; c < 4; ++c) {
    gA[c] = A + (size_t)(m0 + c * 64 + srow) * K + sk;
    gB[c] = BT + (size_t)(n0 + c * 64 + srow) * K + sk;
  }

  // read addresses
  const int lr = lane & 15, lg = lane >> 4;
  const int c0 = ((lg ^ (lr & 7)) << 4);
  const int abase = (wr * 128 + lr) * 128;
  const int bbase = (wc * 64 + lr) * 128;

  f32x4 acc[8][4] = {};
  bf16x8 af[4][2], b01[2][2], b23[2][2];  // round-2 footprint (no spill)

  // ---- prologue: B(0), A(0), B(1); certify through S_Alo(0) ----
  ST_B_LO(bEw, 0);  ST_B_HI(bEw, 0);     // B(0)
  ST_A_LO(aEw, 0);  ST_A_HI(aEw, 0);     // A(0): S_Alo then S_Ahi
  ST_B_LO(bOw, 64); ST_B_HI(bOw, 64);    // B(1)
  VMW(6);  // drains B(0)+S_Alo(0); leaves S_Ahi(0), B(1) in flight
  BAR();

  const int NT = K >> 6;        // K-tiles (both GEMMs: NT even, >= 4)
  const int nIt = NT >> 1;      // 2 tiles per iteration

  for (int it = 0; it < nIt - 1; ++it) {
    const int kO  = (2 * it + 1) << 6;  // tile O
    const int kE2 = (2 * it + 2) << 6;  // tile E' (= E+2)
    const int kO2 = (2 * it + 3) << 6;  // tile O' (= O+2)
    // ---- tile E ----
    // P1: Q1=afl x b01 ; stage S_Alo(O)
    RD_A(af, aE, 0); RD_B(b01, bE, 0); ST_A_LO(aOw, kO);
    BAR(); LGKM0(); QUAD(0, 0, af, b01); BAR();
    // P2: Q2=afl x b23 ; stage S_Ahi(O) ; certify S_Ahi(E) [4-phase cover]
    RD_B(b23, bE, 2); ST_A_HI(aOw, kO);
    BAR(); LGKM0(); QUAD(0, 2, af, b23); VMW(8); BAR();
    // P3: Q3=afh x b23 ; stage S_Blo(E') [B-buf E free since P2-end]
    RD_A(af, aE, 4); ST_B_LO(bEw, kE2);
    BAR(); LGKM0(); QUAD(4, 2, af, b23); BAR();
    // P4: Q4=afh x b01 ; stage S_Bhi(E') ; certify B(O)+S_Alo(O)
    ST_B_HI(bEw, kE2);
    BAR(); QUAD(4, 0, af, b01); VMW(6); BAR();
    // ---- tile O (mirror) ----
    RD_A(af, aO, 0); RD_B(b01, bO, 0); ST_A_LO(aEw, kE2);
    BAR(); LGKM0(); QUAD(0, 0, af, b01); BAR();
    RD_B(b23, bO, 2); ST_A_HI(aEw, kE2);
    BAR(); LGKM0(); QUAD(0, 2, af, b23); VMW(8); BAR();
    RD_A(af, aO, 4); ST_B_LO(bOw, kO2);
    BAR(); LGKM0(); QUAD(4, 2, af, b23); BAR();
    ST_B_HI(bOw, kO2);
    BAR(); QUAD(4, 0, af, b01); VMW(6); BAR();
  }

  // ---- peeled last iteration (tiles NT-2, NT-1): drain 8 -> 2 -> 0 ----
  {
    const int kO = (NT - 1) << 6;
    RD_A(af, aE, 0); RD_B(b01, bE, 0); ST_A_LO(aOw, kO);
    BAR(); LGKM0(); QUAD(0, 0, af, b01); BAR();
    RD_B(b23, bE, 2); ST_A_HI(aOw, kO);
    BAR(); LGKM0(); QUAD(0, 2, af, b23); VMW(8); BAR();
    RD_A(af, aE, 4);
    BAR(); LGKM0(); QUAD(4, 2, af, b23); BAR();
    BAR(); QUAD(4, 0, af, b01); VMW(2); BAR();
    RD_A(af, aO, 0); RD_B(b01, bO, 0);
    BAR(); LGKM0(); QUAD(0, 0, af, b01); BAR();
    RD_B(b23, bO, 2);
    BAR(); LGKM0(); QUAD(0, 2, af, b23); VMW(0); BAR();
    RD_A(af, aO, 4);
    BAR(); LGKM0(); QUAD(4, 2, af, b23); BAR();
    QUAD(4, 0, af, b01);
  }

  // ---- epilogue. C/D frag: col = lane&15, row = (lane>>4)*4 + j ----
  const int ccol = n0 + wc * 64;
  const int crow = m0 + wr * 128;
  float bv[4];
#pragma unroll
  for (int n = 0; n < 4; ++n) bv[n] = bias[ccol + n * 16 + lr];

  if (RELU_BF16) {
    unsigned short* O = (unsigned short*)Cout;
#pragma unroll
    for (int m = 0; m < 8; ++m)
#pragma unroll
      for (int j = 0; j < 4; ++j) {
        size_t r = (size_t)(crow + m * 16 + lg * 4 + j) * N;
#pragma unroll
        for (int n = 0; n < 4; ++n) {
          float v = acc[m][n][j] + bv[n];
          O[r + ccol + n * 16 + lr] = f2bf(fmaxf(v, 0.0f));
        }
      }
  } else {
    float* O = (float*)Cout;
#pragma unroll
    for (int m = 0; m < 8; ++m)
#pragma unroll
      for (int j = 0; j < 4; ++j) {
        size_t r = (size_t)(crow + m * 16 + lg * 4 + j) * N;
#pragma unroll
        for (int n = 0; n < 4; ++n)
          O[r + ccol + n * 16 + lr] = acc[m][n][j] + bv[n];
      }
  }
}

// ---------------- launch ----------------

extern "C" void kernel_launch(void* const* d_in, const int* in_sizes, int n_in,
                              void* d_out, int out_size, void* d_ws,
                              size_t ws_size, hipStream_t stream) {
  const float* x  = (const float*)d_in[0];   // [16384,1024]
  const float* W1 = (const float*)d_in[1];   // [1024,4096]
  const float* b1 = (const float*)d_in[2];   // [4096]
  const float* W2 = (const float*)d_in[3];   // [4096,1024]
  const float* b2 = (const float*)d_in[4];   // [1024]
  float* out = (float*)d_out;                // [16384,1024] f32

  const int B = 16384, DIN = 1024, DH = 4096, DOUT = 1024;

  size_t need = (size_t)B * DIN * 2 + (size_t)DIN * DH * 2 +
                (size_t)DH * DOUT * 2 + (size_t)B * DH * 2;
  if (ws_size < need) return;

  char* ws = (char*)d_ws;
  unsigned short* xb  = (unsigned short*)ws;  ws += (size_t)B * DIN * 2;
  unsigned short* w1t = (unsigned short*)ws;  ws += (size_t)DIN * DH * 2;  // [DH][DIN]
  unsigned short* w2t = (unsigned short*)ws;  ws += (size_t)DH * DOUT * 2; // [DOUT][DH]
  unsigned short* h   = (unsigned short*)ws;                               // [B][DH]

  hipFuncSetAttribute((const void*)gemm256<true>,
                      hipFuncAttributeMaxDynamicSharedMemorySize, 131072);
  hipFuncSetAttribute((const void*)gemm256<false>,
                      hipFuncAttributeMaxDynamicSharedMemorySize, 131072);

  int n4 = B * DIN / 4;
  cvt_f32_bf16<<<n4 / 256, 256, 0, stream>>>((const float4*)x, (ushort4*)xb, n4);
  transpose_f32_bf16<<<dim3(DH / 32, DIN / 32), dim3(32, 8), 0, stream>>>(W1, w1t, DIN, DH);
  transpose_f32_bf16<<<dim3(DOUT / 32, DH / 32), dim3(32, 8), 0, stream>>>(W2, w2t, DH, DOUT);

  // h = relu(x @ W1 + b1) : M=16384, N=4096, K=1024 (NT=16)
  gemm256<true><<<dim3((B / 256) * (DH / 256)), 512, 131072, stream>>>(
      xb, w1t, b1, h, B, DH, DIN, 4);
  // out = h @ W2 + b2     : M=16384, N=1024, K=4096 (NT=64)
  gemm256<false><<<dim3((B / 256) * (DOUT / 256)), 512, 131072, stream>>>(
      h, w2t, b2, out, B, DOUT, DH, 2);
}

// Round 5
// 279.918 us; speedup vs baseline: 1.9623x; 1.0017x over previous
//
#include <hip/hip_runtime.h>
#include <hip/hip_bf16.h>
#include <stdint.h>

// LimitRegressor = relu(x@W1+b1)@W2+b2 followed by a fixed-point iteration
// whose unique fixed point is y*=out (tanh contraction, global early-exit at
// eps=1e-6 fires at k~13 with residual < 3e-7 << the 6.09e-2 threshold).
// So we emit out directly: two bf16 MFMA GEMMs.
//
// GEMM: 256x256 tile, BK=64, 8 waves (2Mx4N), double-buffered 128KiB LDS.
// 4 phases per K-tile, ONE barrier per phase, NO blanket lgkmcnt drains
// (compiler emits fine-grained per-operand lgkmcnt), ONE counted vmcnt per
// K-tile (VMW(4) at P4, leaving next-next B in flight). Stages: A(t+1) at
// P1/P2, B(t+2) at P3/P4. Zero-skew property of 1-barrier-per-phase makes
// all LDS overwrite hazards >= 1 full phase apart. T1 XCD swizzle, T2 LDS
// XOR swizzle (conflict-free, verified 0 in rocprof), T5 setprio.

#define DEV __device__ __forceinline__

typedef short bf16x8 __attribute__((ext_vector_type(8)));
typedef float f32x4 __attribute__((ext_vector_type(4)));

typedef __attribute__((address_space(1))) const unsigned char* gptr1_t;
typedef __attribute__((address_space(3))) unsigned char* lptr3_t;

DEV void async_copy16(const void* g, void* l) {
  __builtin_amdgcn_global_load_lds((gptr1_t)g, (lptr3_t)l, 16, 0, 0);
}

DEV unsigned short f2bf(float f) {
  union { float f; unsigned u; } v; v.f = f;
  unsigned u = v.u + 0x7FFFu + ((v.u >> 16) & 1u);  // RNE
  return (unsigned short)(u >> 16);
}

#define BAR()  __builtin_amdgcn_s_barrier()
#define VMW(n) asm volatile("s_waitcnt vmcnt(" #n ")" ::: "memory")

// ---------------- prep kernels ----------------

__global__ void cvt_f32_bf16(const float4* __restrict__ in,
                             ushort4* __restrict__ out, int n4) {
  int i = blockIdx.x * blockDim.x + threadIdx.x;
  if (i >= n4) return;
  float4 v = in[i];
  ushort4 o;
  o.x = f2bf(v.x); o.y = f2bf(v.y); o.z = f2bf(v.z); o.w = f2bf(v.w);
  out[i] = o;
}

// f32 [R][C] row-major  ->  bf16 [C][R] row-major (W -> W^T as bf16)
__global__ void transpose_f32_bf16(const float* __restrict__ in,
                                   unsigned short* __restrict__ out,
                                   int R, int C) {
  __shared__ float tile[32][33];
  int c0 = blockIdx.x * 32, r0 = blockIdx.y * 32;
  int tx = threadIdx.x, ty = threadIdx.y;  // block (32, 8)
#pragma unroll
  for (int i = 0; i < 32; i += 8)
    tile[ty + i][tx] = in[(long)(r0 + ty + i) * C + (c0 + tx)];
  __syncthreads();
#pragma unroll
  for (int i = 0; i < 32; i += 8)
    out[(long)(c0 + ty + i) * R + (r0 + tx)] = f2bf(tile[tx][ty + i]);
}

// ---------------- 256x256 8-wave GEMM, C = A * BT^T + bias ----------------
// LDS per operand per buf: 4 chunks of 8KB; chunk c = rows [c*64,c*64+64) x
// k[0,64) bf16, 16B-chunk XOR swizzle: LDS[row][c16] = global k-chunk
// (c16 ^ (row&7)). Staged with pre-swizzled global source (both-sides rule).

#define LDA(base, m, ks) \
  (*(const bf16x8*)((base) + abase + (m) * 2048 + (c0 ^ ((ks) << 6))))
#define LDB(base, n, ks) \
  (*(const bf16x8*)((base) + bbase + (n) * 2048 + (c0 ^ ((ks) << 6))))

#define RD_A(dst, base, m0_)                                   \
  _Pragma("unroll") for (int m_ = 0; m_ < 4; ++m_) {           \
    dst[m_][0] = LDA(base, (m0_) + m_, 0);                     \
    dst[m_][1] = LDA(base, (m0_) + m_, 1);                     \
  }
#define RD_B(dst, base, n0_)                                   \
  _Pragma("unroll") for (int n_ = 0; n_ < 2; ++n_) {           \
    dst[n_][0] = LDB(base, (n0_) + n_, 0);                     \
    dst[n_][1] = LDB(base, (n0_) + n_, 1);                     \
  }

#define QUAD(MB, NB, AF, BF)                                                \
  do {                                                                      \
    __builtin_amdgcn_s_setprio(1);                                          \
    _Pragma("unroll") for (int m_ = 0; m_ < 4; ++m_)                        \
    _Pragma("unroll") for (int n_ = 0; n_ < 2; ++n_) {                      \
      acc[(MB) + m_][(NB) + n_] = __builtin_amdgcn_mfma_f32_16x16x32_bf16(  \
          AF[m_][0], BF[n_][0], acc[(MB) + m_][(NB) + n_], 0, 0, 0);        \
      acc[(MB) + m_][(NB) + n_] = __builtin_amdgcn_mfma_f32_16x16x32_bf16(  \
          AF[m_][1], BF[n_][1], acc[(MB) + m_][(NB) + n_], 0, 0, 0);        \
    }                                                                       \
    __builtin_amdgcn_s_setprio(0);                                          \
  } while (0)

// stage macros: dstw = per-wave LDS base (buf base + wave*1024), koff = elems
#define ST_A_LO(dstw, koff) { async_copy16(gA[0] + (koff), (dstw));          \
                              async_copy16(gA[2] + (koff), (dstw) + 16384); }
#define ST_A_HI(dstw, koff) { async_copy16(gA[1] + (koff), (dstw) + 8192);   \
                              async_copy16(gA[3] + (koff), (dstw) + 24576); }
#define ST_B_LO(dstw, koff) { async_copy16(gB[0] + (koff), (dstw));          \
                              async_copy16(gB[1] + (koff), (dstw) + 8192); }
#define ST_B_HI(dstw, koff) { async_copy16(gB[2] + (koff), (dstw) + 16384);  \
                              async_copy16(gB[3] + (koff), (dstw) + 24576); }

template <bool RELU_BF16>
__global__ __launch_bounds__(512, 2)
void gemm256(const unsigned short* __restrict__ A,   // bf16 [M][K]
             const unsigned short* __restrict__ BT,  // bf16 [N][K]
             const float* __restrict__ bias,         // [N]
             void* __restrict__ Cout,                // bf16 or f32 [M][N]
             int M, int N, int K, int nbn_shift) {
  extern __shared__ char lds[];
  const char* aE = lds;                 // A buf, even tiles
  const char* aO = lds + 32768;         // A buf, odd tiles
  const char* bE = lds + 65536;         // B buf, even
  const char* bO = lds + 98304;         // B buf, odd

  const int tid = threadIdx.x;
  const int wave = tid >> 6, lane = tid & 63;
  const int wr = wave >> 2, wc = wave & 3;  // 2x4 waves, each 128x64 out

  char* aEw = (char*)aE + wave * 1024;
  char* aOw = (char*)aO + wave * 1024;
  char* bEw = (char*)bE + wave * 1024;
  char* bOw = (char*)bO + wave * 1024;

  // T1: XCD-aware block swizzle (grids here are multiples of 8)
  const int nwg = gridDim.x;
  const int wg = blockIdx.x;
  const int swz = (wg & 7) * (nwg >> 3) + (wg >> 3);
  const int bm = swz >> nbn_shift;
  const int bn = swz & ((1 << nbn_shift) - 1);
  const int m0 = bm << 8, n0 = bn << 8;

  // staging addresses (pre-swizzled global source, linear LDS dest)
  const int srow = tid >> 3;
  const int sk = ((tid & 7) ^ (srow & 7)) << 3;
  const unsigned short* gA[4];
  const unsigned short* gB[4];
#pragma unroll
  for (int c = 0; c < 4; ++c) {
    gA[c] = A + (size_t)(m0 + c * 64 + srow) * K + sk;
    gB[c] = BT + (size_t)(n0 + c * 64 + srow) * K + sk;
  }

  // read addresses
  const int lr = lane & 15, lg = lane >> 4;
  const int c0 = ((lg ^ (lr & 7)) << 4);
  const int abase = (wr * 128 + lr) * 128;
  const int bbase = (wc * 64 + lr) * 128;

  f32x4 acc[8][4] = {};
  bf16x8 af[4][2], b01[2][2], b23[2][2];  // no-spill footprint

  // ---- prologue: B(0), A(0), B(1); certify B(0)+A(0), leave B(1) ----
  ST_B_LO(bEw, 0);  ST_B_HI(bEw, 0);     // B(0)
  ST_A_LO(aEw, 0);  ST_A_HI(aEw, 0);     // A(0)
  ST_B_LO(bOw, 64); ST_B_HI(bOw, 64);    // B(1)
  VMW(4);
  BAR();

  const int NT = K >> 6;        // K-tiles (both GEMMs: NT even, >= 4)

  for (int it = 0; it < (NT - 2) / 2; ++it) {
    const int kA  = (2 * it + 1) << 6;  // A(t+1) for tile E
    const int kB  = (2 * it + 2) << 6;  // B(t+2) for tile E
    const int kA2 = (2 * it + 2) << 6;  // A(t+1) for tile O
    const int kB2 = (2 * it + 3) << 6;  // B(t+2) for tile O
    // ---- tile E = 2it ----
    RD_A(af, aE, 0); RD_B(b01, bE, 0); ST_A_LO(aOw, kA);
    QUAD(0, 0, af, b01); BAR();
    RD_B(b23, bE, 2); ST_A_HI(aOw, kA);
    QUAD(0, 2, af, b23); BAR();
    RD_A(af, aE, 4); ST_B_LO(bEw, kB);
    QUAD(4, 2, af, b23); BAR();
    ST_B_HI(bEw, kB);
    QUAD(4, 0, af, b01); VMW(4); BAR();
    // ---- tile O = 2it+1 ----
    RD_A(af, aO, 0); RD_B(b01, bO, 0); ST_A_LO(aEw, kA2);
    QUAD(0, 0, af, b01); BAR();
    RD_B(b23, bO, 2); ST_A_HI(aEw, kA2);
    QUAD(0, 2, af, b23); BAR();
    RD_A(af, aO, 4); ST_B_LO(bOw, kB2);
    QUAD(4, 2, af, b23); BAR();
    ST_B_HI(bOw, kB2);
    QUAD(4, 0, af, b01); VMW(4); BAR();
  }

  // ---- peeled last two tiles (NT-2 even, NT-1 odd): drain to 0 once ----
  {
    const int kL = (NT - 1) << 6;       // A(NT-1)
    // tile NT-2
    RD_A(af, aE, 0); RD_B(b01, bE, 0); ST_A_LO(aOw, kL);
    QUAD(0, 0, af, b01); BAR();
    RD_B(b23, bE, 2); ST_A_HI(aOw, kL);
    QUAD(0, 2, af, b23); BAR();
    RD_A(af, aE, 4);
    QUAD(4, 2, af, b23); BAR();
    QUAD(4, 0, af, b01); VMW(0); BAR();
    // tile NT-1 (pure compute)
    RD_A(af, aO, 0); RD_B(b01, bO, 0);
    QUAD(0, 0, af, b01); BAR();
    RD_B(b23, bO, 2);
    QUAD(0, 2, af, b23); BAR();
    RD_A(af, aO, 4);
    QUAD(4, 2, af, b23); BAR();
    QUAD(4, 0, af, b01);
  }

  // ---- epilogue. C/D frag: col = lane&15, row = (lane>>4)*4 + j ----
  const int ccol = n0 + wc * 64;
  const int crow = m0 + wr * 128;
  float bv[4];
#pragma unroll
  for (int n = 0; n < 4; ++n) bv[n] = bias[ccol + n * 16 + lr];

  if (RELU_BF16) {
    unsigned short* O = (unsigned short*)Cout;
#pragma unroll
    for (int m = 0; m < 8; ++m)
#pragma unroll
      for (int j = 0; j < 4; ++j) {
        size_t r = (size_t)(crow + m * 16 + lg * 4 + j) * N;
#pragma unroll
        for (int n = 0; n < 4; ++n) {
          float v = acc[m][n][j] + bv[n];
          O[r + ccol + n * 16 + lr] = f2bf(fmaxf(v, 0.0f));
        }
      }
  } else {
    float* O = (float*)Cout;
#pragma unroll
    for (int m = 0; m < 8; ++m)
#pragma unroll
      for (int j = 0; j < 4; ++j) {
        size_t r = (size_t)(crow + m * 16 + lg * 4 + j) * N;
#pragma unroll
        for (int n = 0; n < 4; ++n)
          O[r + ccol + n * 16 + lr] = acc[m][n][j] + bv[n];
      }
  }
}

// ---------------- launch ----------------

extern "C" void kernel_launch(void* const* d_in, const int* in_sizes, int n_in,
                              void* d_out, int out_size, void* d_ws,
                              size_t ws_size, hipStream_t stream) {
  const float* x  = (const float*)d_in[0];   // [16384,1024]
  const float* W1 = (const float*)d_in[1];   // [1024,4096]
  const float* b1 = (const float*)d_in[2];   // [4096]
  const float* W2 = (const float*)d_in[3];   // [4096,1024]
  const float* b2 = (const float*)d_in[4];   // [1024]
  float* out = (float*)d_out;                // [16384,1024] f32

  const int B = 16384, DIN = 1024, DH = 4096, DOUT = 1024;

  size_t need = (size_t)B * DIN * 2 + (size_t)DIN * DH * 2 +
                (size_t)DH * DOUT * 2 + (size_t)B * DH * 2;
  if (ws_size < need) return;

  char* ws = (char*)d_ws;
  unsigned short* xb  = (unsigned short*)ws;  ws += (size_t)B * DIN * 2;
  unsigned short* w1t = (unsigned short*)ws;  ws += (size_t)DIN * DH * 2;  // [DH][DIN]
  unsigned short* w2t = (unsigned short*)ws;  ws += (size_t)DH * DOUT * 2; // [DOUT][DH]
  unsigned short* h   = (unsigned short*)ws;                               // [B][DH]

  hipFuncSetAttribute((const void*)gemm256<true>,
                      hipFuncAttributeMaxDynamicSharedMemorySize, 131072);
  hipFuncSetAttribute((const void*)gemm256<false>,
                      hipFuncAttributeMaxDynamicSharedMemorySize, 131072);

  int n4 = B * DIN / 4;
  cvt_f32_bf16<<<n4 / 256, 256, 0, stream>>>((const float4*)x, (ushort4*)xb, n4);
  transpose_f32_bf16<<<dim3(DH / 32, DIN / 32), dim3(32, 8), 0, stream>>>(W1, w1t, DIN, DH);
  transpose_f32_bf16<<<dim3(DOUT / 32, DH / 32), dim3(32, 8), 0, stream>>>(W2, w2t, DH, DOUT);

  // h = relu(x @ W1 + b1) : M=16384, N=4096, K=1024 (NT=16)
  gemm256<true><<<dim3((B / 256) * (DH / 256)), 512, 131072, stream>>>(
      xb, w1t, b1, h, B, DH, DIN, 4);
  // out = h @ W2 + b2     : M=16384, N=1024, K=4096 (NT=64)
  gemm256<false><<<dim3((B / 256) * (DOUT / 256)), 512, 131072, stream>>>(
      h, w2t, b2, out, B, DOUT, DH, 2);
}

// Round 6
// 274.452 us; speedup vs baseline: 2.0014x; 1.0199x over previous
//
#include <hip/hip_runtime.h>
#include <hip/hip_bf16.h>
#include <stdint.h>

// LimitRegressor = relu(x@W1+b1)@W2+b2 followed by a fixed-point iteration
// whose unique fixed point is y*=out (tanh contraction, global early-exit at
// eps=1e-6 fires at k~13 with residual < 3e-7 << the 6.09e-2 threshold).
// So we emit out directly: two bf16 MFMA GEMMs.
//
// GEMM: 256x256 tile, BK=64, 8 waves (2Mx4N), double-buffered 128KiB LDS.
// TWO phases per K-tile (32-MFMA runs), one barrier per phase, ONE counted
// vmcnt per tile (VMW(4): drains A(t+1)+B(t+1), leaves B(t+2) in flight).
// Stages: A(t+1) in Ph1, B(t+2) in Ph2. No blanket lgkmcnt drains - the
// compiler emits fine-grained per-operand waits so early MFMAs start while
// later reads return. Register footprint pinned at 128 VGPR + 128 AGPR
// (2 waves/SIMD cap - no read-ahead possible without spill, round-3 lesson).
// T1 XCD swizzle, T2 LDS XOR swizzle (0 conflicts measured), T5 setprio.

#define DEV __device__ __forceinline__

typedef short bf16x8 __attribute__((ext_vector_type(8)));
typedef float f32x4 __attribute__((ext_vector_type(4)));

typedef __attribute__((address_space(1))) const unsigned char* gptr1_t;
typedef __attribute__((address_space(3))) unsigned char* lptr3_t;

DEV void async_copy16(const void* g, void* l) {
  __builtin_amdgcn_global_load_lds((gptr1_t)g, (lptr3_t)l, 16, 0, 0);
}

DEV unsigned short f2bf(float f) {
  union { float f; unsigned u; } v; v.f = f;
  unsigned u = v.u + 0x7FFFu + ((v.u >> 16) & 1u);  // RNE
  return (unsigned short)(u >> 16);
}

#define BAR()  __builtin_amdgcn_s_barrier()
#define VMW(n) asm volatile("s_waitcnt vmcnt(" #n ")" ::: "memory")

// ---------------- prep kernels ----------------

__global__ void cvt_f32_bf16(const float4* __restrict__ in,
                             ushort4* __restrict__ out, int n4) {
  int i = blockIdx.x * blockDim.x + threadIdx.x;
  if (i >= n4) return;
  float4 v = in[i];
  ushort4 o;
  o.x = f2bf(v.x); o.y = f2bf(v.y); o.z = f2bf(v.z); o.w = f2bf(v.w);
  out[i] = o;
}

// f32 [R][C] row-major  ->  bf16 [C][R] row-major (W -> W^T as bf16)
__global__ void transpose_f32_bf16(const float* __restrict__ in,
                                   unsigned short* __restrict__ out,
                                   int R, int C) {
  __shared__ float tile[32][33];
  int c0 = blockIdx.x * 32, r0 = blockIdx.y * 32;
  int tx = threadIdx.x, ty = threadIdx.y;  // block (32, 8)
#pragma unroll
  for (int i = 0; i < 32; i += 8)
    tile[ty + i][tx] = in[(long)(r0 + ty + i) * C + (c0 + tx)];
  __syncthreads();
#pragma unroll
  for (int i = 0; i < 32; i += 8)
    out[(long)(c0 + ty + i) * R + (r0 + tx)] = f2bf(tile[tx][ty + i]);
}

// ---------------- 256x256 8-wave GEMM, C = A * BT^T + bias ----------------
// LDS per operand per buf: 4 chunks of 8KB; chunk c = rows [c*64,c*64+64) x
// k[0,64) bf16, 16B-chunk XOR swizzle: LDS[row][c16] = global k-chunk
// (c16 ^ (row&7)). Staged with pre-swizzled global source (both-sides rule).

#define LDA(base, m, ks) \
  (*(const bf16x8*)((base) + abase + (m) * 2048 + (c0 ^ ((ks) << 6))))
#define LDB(base, n, ks) \
  (*(const bf16x8*)((base) + bbase + (n) * 2048 + (c0 ^ ((ks) << 6))))

#define RD_A(dst, base, m0_)                                   \
  _Pragma("unroll") for (int m_ = 0; m_ < 4; ++m_) {           \
    dst[m_][0] = LDA(base, (m0_) + m_, 0);                     \
    dst[m_][1] = LDA(base, (m0_) + m_, 1);                     \
  }
#define RD_B(dst, base, n0_)                                   \
  _Pragma("unroll") for (int n_ = 0; n_ < 2; ++n_) {           \
    dst[n_][0] = LDB(base, (n0_) + n_, 0);                     \
    dst[n_][1] = LDB(base, (n0_) + n_, 1);                     \
  }

#define QUAD(MB, NB, AF, BF)                                                \
  do {                                                                      \
    __builtin_amdgcn_s_setprio(1);                                          \
    _Pragma("unroll") for (int m_ = 0; m_ < 4; ++m_)                        \
    _Pragma("unroll") for (int n_ = 0; n_ < 2; ++n_) {                      \
      acc[(MB) + m_][(NB) + n_] = __builtin_amdgcn_mfma_f32_16x16x32_bf16(  \
          AF[m_][0], BF[n_][0], acc[(MB) + m_][(NB) + n_], 0, 0, 0);        \
      acc[(MB) + m_][(NB) + n_] = __builtin_amdgcn_mfma_f32_16x16x32_bf16(  \
          AF[m_][1], BF[n_][1], acc[(MB) + m_][(NB) + n_], 0, 0, 0);        \
    }                                                                       \
    __builtin_amdgcn_s_setprio(0);                                          \
  } while (0)

// stage macros: dstw = per-wave LDS base (buf base + wave*1024), koff = elems
#define ST_A_LO(dstw, koff) { async_copy16(gA[0] + (koff), (dstw));          \
                              async_copy16(gA[2] + (koff), (dstw) + 16384); }
#define ST_A_HI(dstw, koff) { async_copy16(gA[1] + (koff), (dstw) + 8192);   \
                              async_copy16(gA[3] + (koff), (dstw) + 24576); }
#define ST_B_LO(dstw, koff) { async_copy16(gB[0] + (koff), (dstw));          \
                              async_copy16(gB[1] + (koff), (dstw) + 8192); }
#define ST_B_HI(dstw, koff) { async_copy16(gB[2] + (koff), (dstw) + 16384);  \
                              async_copy16(gB[3] + (koff), (dstw) + 24576); }

template <bool RELU_BF16>
__global__ __launch_bounds__(512, 2)
void gemm256(const unsigned short* __restrict__ A,   // bf16 [M][K]
             const unsigned short* __restrict__ BT,  // bf16 [N][K]
             const float* __restrict__ bias,         // [N]
             void* __restrict__ Cout,                // bf16 or f32 [M][N]
             int M, int N, int K, int nbn_shift) {
  extern __shared__ char lds[];
  const char* aE = lds;                 // A buf, even tiles
  const char* aO = lds + 32768;         // A buf, odd tiles
  const char* bE = lds + 65536;         // B buf, even
  const char* bO = lds + 98304;         // B buf, odd

  const int tid = threadIdx.x;
  const int wave = tid >> 6, lane = tid & 63;
  const int wr = wave >> 2, wc = wave & 3;  // 2x4 waves, each 128x64 out

  char* aEw = (char*)aE + wave * 1024;
  char* aOw = (char*)aO + wave * 1024;
  char* bEw = (char*)bE + wave * 1024;
  char* bOw = (char*)bO + wave * 1024;

  // T1: XCD-aware block swizzle (grids here are multiples of 8)
  const int nwg = gridDim.x;
  const int wg = blockIdx.x;
  const int swz = (wg & 7) * (nwg >> 3) + (wg >> 3);
  const int bm = swz >> nbn_shift;
  const int bn = swz & ((1 << nbn_shift) - 1);
  const int m0 = bm << 8, n0 = bn << 8;

  // staging addresses (pre-swizzled global source, linear LDS dest)
  const int srow = tid >> 3;
  const int sk = ((tid & 7) ^ (srow & 7)) << 3;
  const unsigned short* gA[4];
  const unsigned short* gB[4];
#pragma unroll
  for (int c = 0; c < 4; ++c) {
    gA[c] = A + (size_t)(m0 + c * 64 + srow) * K + sk;
    gB[c] = BT + (size_t)(n0 + c * 64 + srow) * K + sk;
  }

  // read addresses
  const int lr = lane & 15, lg = lane >> 4;
  const int c0 = ((lg ^ (lr & 7)) << 4);
  const int abase = (wr * 128 + lr) * 128;
  const int bbase = (wc * 64 + lr) * 128;

  f32x4 acc[8][4] = {};
  bf16x8 af[4][2], b01[2][2], b23[2][2];  // no-spill footprint

  // ---- prologue: B(0), A(0), B(1); certify B(0)+A(0), leave B(1) ----
  ST_B_LO(bEw, 0);  ST_B_HI(bEw, 0);     // B(0)
  ST_A_LO(aEw, 0);  ST_A_HI(aEw, 0);     // A(0)
  ST_B_LO(bOw, 64); ST_B_HI(bOw, 64);    // B(1)
  VMW(4);
  BAR();

  const int NT = K >> 6;        // K-tiles (both GEMMs: NT even, >= 4)

  for (int it = 0; it < (NT - 2) / 2; ++it) {
    const int kE = (2 * it) << 6;
    // ---- tile E = 2it ----
    // Ph1: quads (0,0)+(0,2); stage A(E+1)
    RD_B(b01, bE, 0); RD_A(af, aE, 0); RD_B(b23, bE, 2);
    ST_A_LO(aOw, kE + 64); ST_A_HI(aOw, kE + 64);
    QUAD(0, 0, af, b01); QUAD(0, 2, af, b23);
    BAR();
    // Ph2: quads (4,2)+(4,0); stage B(E+2); certify A(E+1)+B(E+1)
    RD_A(af, aE, 4);
    ST_B_LO(bEw, kE + 128); ST_B_HI(bEw, kE + 128);
    QUAD(4, 2, af, b23); QUAD(4, 0, af, b01);
    VMW(4); BAR();
    // ---- tile O = 2it+1 ----
    RD_B(b01, bO, 0); RD_A(af, aO, 0); RD_B(b23, bO, 2);
    ST_A_LO(aEw, kE + 128); ST_A_HI(aEw, kE + 128);
    QUAD(0, 0, af, b01); QUAD(0, 2, af, b23);
    BAR();
    RD_A(af, aO, 4);
    ST_B_LO(bOw, kE + 192); ST_B_HI(bOw, kE + 192);
    QUAD(4, 2, af, b23); QUAD(4, 0, af, b01);
    VMW(4); BAR();
  }

  // ---- peeled last two tiles (NT-2 even, NT-1 odd) ----
  {
    const int kL = (NT - 1) << 6;       // A(NT-1)
    // tile NT-2
    RD_B(b01, bE, 0); RD_A(af, aE, 0); RD_B(b23, bE, 2);
    ST_A_LO(aOw, kL); ST_A_HI(aOw, kL);
    QUAD(0, 0, af, b01); QUAD(0, 2, af, b23);
    BAR();
    RD_A(af, aE, 4);
    QUAD(4, 2, af, b23); QUAD(4, 0, af, b01);
    VMW(0); BAR();
    // tile NT-1 (pure compute)
    RD_B(b01, bO, 0); RD_A(af, aO, 0); RD_B(b23, bO, 2);
    QUAD(0, 0, af, b01); QUAD(0, 2, af, b23);
    BAR();
    RD_A(af, aO, 4);
    QUAD(4, 2, af, b23); QUAD(4, 0, af, b01);
  }

  // ---- epilogue. C/D frag: col = lane&15, row = (lane>>4)*4 + j ----
  const int ccol = n0 + wc * 64;
  const int crow = m0 + wr * 128;
  float bv[4];
#pragma unroll
  for (int n = 0; n < 4; ++n) bv[n] = bias[ccol + n * 16 + lr];

  if (RELU_BF16) {
    unsigned short* O = (unsigned short*)Cout;
#pragma unroll
    for (int m = 0; m < 8; ++m)
#pragma unroll
      for (int j = 0; j < 4; ++j) {
        size_t r = (size_t)(crow + m * 16 + lg * 4 + j) * N;
#pragma unroll
        for (int n = 0; n < 4; ++n) {
          float v = acc[m][n][j] + bv[n];
          O[r + ccol + n * 16 + lr] = f2bf(fmaxf(v, 0.0f));
        }
      }
  } else {
    float* O = (float*)Cout;
#pragma unroll
    for (int m = 0; m < 8; ++m)
#pragma unroll
      for (int j = 0; j < 4; ++j) {
        size_t r = (size_t)(crow + m * 16 + lg * 4 + j) * N;
#pragma unroll
        for (int n = 0; n < 4; ++n)
          O[r + ccol + n * 16 + lr] = acc[m][n][j] + bv[n];
      }
  }
}

// ---------------- launch ----------------

extern "C" void kernel_launch(void* const* d_in, const int* in_sizes, int n_in,
                              void* d_out, int out_size, void* d_ws,
                              size_t ws_size, hipStream_t stream) {
  const float* x  = (const float*)d_in[0];   // [16384,1024]
  const float* W1 = (const float*)d_in[1];   // [1024,4096]
  const float* b1 = (const float*)d_in[2];   // [4096]
  const float* W2 = (const float*)d_in[3];   // [4096,1024]
  const float* b2 = (const float*)d_in[4];   // [1024]
  float* out = (float*)d_out;                // [16384,1024] f32

  const int B = 16384, DIN = 1024, DH = 4096, DOUT = 1024;

  size_t need = (size_t)B * DIN * 2 + (size_t)DIN * DH * 2 +
                (size_t)DH * DOUT * 2 + (size_t)B * DH * 2;
  if (ws_size < need) return;

  char* ws = (char*)d_ws;
  unsigned short* xb  = (unsigned short*)ws;  ws += (size_t)B * DIN * 2;
  unsigned short* w1t = (unsigned short*)ws;  ws += (size_t)DIN * DH * 2;  // [DH][DIN]
  unsigned short* w2t = (unsigned short*)ws;  ws += (size_t)DH * DOUT * 2; // [DOUT][DH]
  unsigned short* h   = (unsigned short*)ws;                               // [B][DH]

  hipFuncSetAttribute((const void*)gemm256<true>,
                      hipFuncAttributeMaxDynamicSharedMemorySize, 131072);
  hipFuncSetAttribute((const void*)gemm256<false>,
                      hipFuncAttributeMaxDynamicSharedMemorySize, 131072);

  int n4 = B * DIN / 4;
  cvt_f32_bf16<<<n4 / 256, 256, 0, stream>>>((const float4*)x, (ushort4*)xb, n4);
  transpose_f32_bf16<<<dim3(DH / 32, DIN / 32), dim3(32, 8), 0, stream>>>(W1, w1t, DIN, DH);
  transpose_f32_bf16<<<dim3(DOUT / 32, DH / 32), dim3(32, 8), 0, stream>>>(W2, w2t, DH, DOUT);

  // h = relu(x @ W1 + b1) : M=16384, N=4096, K=1024 (NT=16)
  gemm256<true><<<dim3((B / 256) * (DH / 256)), 512, 131072, stream>>>(
      xb, w1t, b1, h, B, DH, DIN, 4);
  // out = h @ W2 + b2     : M=16384, N=1024, K=4096 (NT=64)
  gemm256<false><<<dim3((B / 256) * (DOUT / 256)), 512, 131072, stream>>>(
      h, w2t, b2, out, B, DOUT, DH, 2);
}